// Round 5
// baseline (1379.204 us; speedup 1.0000x reference)
//
#include <hip/hip_runtime.h>

typedef unsigned short ushortT;
typedef __attribute__((ext_vector_type(8))) short short8;
typedef __attribute__((ext_vector_type(4))) float float4v;

__device__ __forceinline__ float bf2f(unsigned short h) {
    unsigned u = ((unsigned)h) << 16;
    return __builtin_bit_cast(float, u);
}
__device__ __forceinline__ unsigned short f2bf(float f) {
    unsigned u = __builtin_bit_cast(unsigned, f);
    u = u + 0x7fffu + ((u >> 16) & 1u);
    return (unsigned short)(u >> 16);
}

// segment loaders: branch folds after unroll (f32 is compile-time per segment)
__device__ __forceinline__ float2 loadc2(bool f32, const void* p, size_t off) {
    if (f32) {
        return *(const float2*)((const float*)p + off);
    } else {
        unsigned v = *(const unsigned*)((const ushortT*)p + off);
        return make_float2(bf2f((unsigned short)v), bf2f((unsigned short)(v >> 16)));
    }
}
__device__ __forceinline__ void loadc8(bool f32, const void* p, size_t off, float o[8]) {
    if (f32) {
        const float* q = (const float*)p + off;
        float4 a = *(const float4*)q;
        float4 b = *(const float4*)(q + 4);
        o[0] = a.x; o[1] = a.y; o[2] = a.z; o[3] = a.w;
        o[4] = b.x; o[5] = b.y; o[6] = b.z; o[7] = b.w;
    } else {
        uint4 v = *(const uint4*)((const ushortT*)p + off);
        unsigned uu[4] = {v.x, v.y, v.z, v.w};
        #pragma unroll
        for (int j = 0; j < 8; j++) o[j] = bf2f((unsigned short)(uu[j >> 1] >> ((j & 1) * 16)));
    }
}

// ---------------- f32 -> bf16 cast (weights) ----------------

__global__ __launch_bounds__(256) void cast_f32_bf16(const float* __restrict__ in, ushortT* __restrict__ out, int n4) {
    int i = blockIdx.x * 256 + threadIdx.x;
    if (i >= n4) return;
    float4 v = ((const float4*)in)[i];
    ushort4 o;
    o.x = f2bf(v.x); o.y = f2bf(v.y); o.z = f2bf(v.z); o.w = f2bf(v.w);
    ((ushort4*)out)[i] = o;
}

// ---------------- per-row LN stats for f32 x (128 cols) ----------------

__global__ __launch_bounds__(256) void stats_f32(const float* __restrict__ X, float2* __restrict__ ST, int n) {
    int wid = (blockIdx.x * 256 + threadIdx.x) >> 6;
    int lane = threadIdx.x & 63;
    if (wid >= n) return;
    float2 v = *(const float2*)(X + (size_t)wid * 128 + lane * 2);
    float s = v.x + v.y, ss = v.x * v.x + v.y * v.y;
    #pragma unroll
    for (int d = 1; d < 64; d <<= 1) { s += __shfl_xor(s, d); ss += __shfl_xor(ss, d); }
    if (lane == 0) ST[wid] = make_float2(s, ss);
}

// ---------------- CSR build ----------------

__global__ __launch_bounds__(256) void zero_ints(int* p, int n) {
    int i = blockIdx.x * 256 + threadIdx.x;
    if (i < n) p[i] = 0;
}

__global__ __launch_bounds__(256) void hist_kernel(const int* __restrict__ dst, int* __restrict__ cnt, int E, int n) {
    int e = blockIdx.x * 256 + threadIdx.x;
    if (e < E) {
        int d = dst[e];
        if ((unsigned)d < (unsigned)n) atomicAdd(&cnt[d], 1);
    }
}

__device__ __forceinline__ int wave_incl_scan(int v, int lane) {
    #pragma unroll
    for (int d = 1; d < 64; d <<= 1) {
        int o = __shfl_up(v, d);
        if (lane >= d) v += o;
    }
    return v;
}

__global__ __launch_bounds__(256) void scanA(const int* __restrict__ cnt, int* __restrict__ out,
                                             int* __restrict__ bsum, int n) {
    __shared__ int wtot[4];
    int tid = threadIdx.x, blk = blockIdx.x;
    int base = blk * 1024 + tid * 4;
    int e[4];
    #pragma unroll
    for (int j = 0; j < 4; j++) { int idx = base + j; e[j] = (idx < n) ? cnt[idx] : 0; }
    int s = e[0] + e[1] + e[2] + e[3];
    int lane = tid & 63, w = tid >> 6;
    int incl = wave_incl_scan(s, lane);
    if (lane == 63) wtot[w] = incl;
    __syncthreads();
    int woff = 0;
    for (int i = 0; i < w; i++) woff += wtot[i];
    int run = woff + incl - s;
    #pragma unroll
    for (int j = 0; j < 4; j++) { int idx = base + j; if (idx < n) out[idx] = run; run += e[j]; }
    if (tid == 0) bsum[blk] = wtot[0] + wtot[1] + wtot[2] + wtot[3];
}

__global__ __launch_bounds__(64) void scanB(int* bsum, int nb) {
    int lane = threadIdx.x;
    int carry = 0;
    for (int base = 0; base < nb; base += 64) {
        int i = base + lane;
        int v = (i < nb) ? bsum[i] : 0;
        int incl = wave_incl_scan(v, lane);
        if (i < nb) bsum[i] = carry + incl - v;
        carry += __shfl(incl, 63);
    }
}

__global__ __launch_bounds__(256) void scanC(int* __restrict__ out, const int* __restrict__ bsum, int n, int E) {
    int blk = blockIdx.x, tid = threadIdx.x;
    int off = bsum[blk];
    int base = blk * 1024 + tid * 4;
    #pragma unroll
    for (int j = 0; j < 4; j++) { int idx = base + j; if (idx < n) out[idx] += off; }
    if (blk == 0 && tid == 0) out[n] = E;
}

__global__ __launch_bounds__(256) void dinv_cur_kernel(const int* __restrict__ rowptr, float* __restrict__ dinv,
                                                       int* __restrict__ cur, int n) {
    int i = blockIdx.x * 256 + threadIdx.x;
    if (i < n) {
        int deg = rowptr[i + 1] - rowptr[i] + 1;  // +1 self loop
        dinv[i] = rsqrtf((float)max(deg, 1));
        cur[i] = rowptr[i];
    }
}

__global__ __launch_bounds__(256) void fill_kernel(const int* __restrict__ src, const int* __restrict__ dst,
                                                   int* __restrict__ cur, int* __restrict__ colv, int E, int n) {
    int e = blockIdx.x * 256 + threadIdx.x;
    if (e < E) {
        int d = dst[e];
        if ((unsigned)d < (unsigned)n) {
            int p = atomicAdd(&cur[d], 1);
            colv[p] = src[e];
        }
    }
}

// ---------------- fused FastKAN transform (no LDS; stats precomputed) ----------------
// Input row = concat of NSEG 128-wide segments; F32MASK bit s => segment s is f32.
// A = [rbf(LN(x)) | silu(x)]  [16rows x 5*DIN] per wave; B = [Ws^T ; Wb^T] (bf16).
template <int NSEG, int DOUT, int F32MASK>
__global__ __launch_bounds__(256) void fkan_kernel(
    const void* __restrict__ X0, int s0,
    const void* __restrict__ X1, int s1,
    const void* __restrict__ X2, int s2,
    const float2* __restrict__ ST0, const float2* __restrict__ ST1, const float2* __restrict__ ST2,
    const float* __restrict__ lng, const float* __restrict__ lnb,
    const ushortT* __restrict__ Wsb, const ushortT* __restrict__ Wbb,
    const float* __restrict__ bs, const float* __restrict__ bb,
    ushortT* __restrict__ H, int hstride, int nrows) {
    constexpr int DIN = NSEG * 128;
    constexpr int NT = (DOUT + 15) / 16;
    int tid = threadIdx.x;
    int w = tid >> 6, lane = tid & 63;
    int m = lane & 15, q = lane >> 4;
    int base = blockIdx.x * 64 + w * 16;   // this wave's 16 rows
    int lrow = min(base + m, nrows - 1);   // clamped A-row for loads

    // LN stats from precomputed per-segment (sum, ssq)
    float2 st = ST0[lrow];
    float sum = st.x, ssq = st.y;
    if (NSEG == 3) {
        float2 t1 = ST1[lrow]; sum += t1.x; ssq += t1.y;
        float2 t2 = ST2[lrow]; sum += t2.x; ssq += t2.y;
    }
    float mu = sum * (1.0f / DIN);
    float var = ssq * (1.0f / DIN) - mu * mu;
    float sc = rsqrtf(fmaxf(var, 0.0f) + 1e-5f);

    float4v acc[NT];
    #pragma unroll
    for (int t = 0; t < NT; t++) acc[t] = (float4v){0.f, 0.f, 0.f, 0.f};

    // ---- RBF region: per segment, 16 K-steps of 32 A-cols ----
    #pragma unroll
    for (int seg = 0; seg < NSEG; seg++) {
        const void* Xp = (seg == 0) ? X0 : (seg == 1) ? X1 : X2;
        int str = (seg == 0) ? s0 : (seg == 1) ? s1 : s2;
        bool f32 = ((F32MASK >> seg) & 1) != 0;
        size_t rbase = (size_t)lrow * str;
        for (int kk = 0; kk < 16; kk++) {
            int c0 = kk * 8 + 2 * q;               // col within segment
            float2 xv = loadc2(f32, Xp, rbase + c0);
            int gc = seg * 128 + c0;               // global col (lng/lnb index)
            float2 gv = *(const float2*)(lng + gc);
            float2 bv = *(const float2*)(lnb + gc);
            float z0 = (xv.x - mu) * sc * gv.x + bv.x;
            float z1 = (xv.y - mu) * sc * gv.y + bv.y;
            const float G0 = -2.f, G1 = -2.f / 3.f, G2 = 2.f / 3.f, G3 = 2.f;
            short8 af;
            #pragma unroll
            for (int j = 0; j < 8; j++) {
                float z = (j < 4) ? z0 : z1;
                float g = (j & 3) == 0 ? G0 : (j & 3) == 1 ? G1 : (j & 3) == 2 ? G2 : G3;
                float d = (z - g) * 0.75f;         // 1/DENOM = 3/4
                af[j] = (short)f2bf(__expf(-d * d));
            }
            int ks = seg * 512 + kk * 32;          // A-col base (Ws col)
            #pragma unroll
            for (int t = 0; t < NT; t++) {
                int n = t * 16 + m;
                short8 bfr = (short8){0, 0, 0, 0, 0, 0, 0, 0};
                if ((DOUT % 16 == 0) || (n < DOUT))
                    bfr = *(const short8*)(Wsb + (size_t)n * (4 * DIN) + ks + q * 8);
                acc[t] = __builtin_amdgcn_mfma_f32_16x16x32_bf16(af, bfr, acc[t], 0, 0, 0);
            }
        }
    }

    // ---- SiLU (base) region: per segment, 4 K-steps of 32 ----
    #pragma unroll
    for (int seg = 0; seg < NSEG; seg++) {
        const void* Xp = (seg == 0) ? X0 : (seg == 1) ? X1 : X2;
        int str = (seg == 0) ? s0 : (seg == 1) ? s1 : s2;
        bool f32 = ((F32MASK >> seg) & 1) != 0;
        size_t rbase = (size_t)lrow * str;
        for (int kk = 0; kk < 4; kk++) {
            int cb = kk * 32 + q * 8;              // col within segment
            float xv[8];
            loadc8(f32, Xp, rbase + cb, xv);
            short8 af;
            #pragma unroll
            for (int j = 0; j < 8; j++) {
                float xf = xv[j];
                float sg = 1.0f / (1.0f + __expf(-xf));
                af[j] = (short)f2bf(xf * sg);
            }
            int kofs = seg * 128 + kk * 32;        // col into Wb's DIN space
            #pragma unroll
            for (int t = 0; t < NT; t++) {
                int n = t * 16 + m;
                short8 bfr = (short8){0, 0, 0, 0, 0, 0, 0, 0};
                if ((DOUT % 16 == 0) || (n < DOUT))
                    bfr = *(const short8*)(Wbb + (size_t)n * DIN + kofs + q * 8);
                acc[t] = __builtin_amdgcn_mfma_f32_16x16x32_bf16(af, bfr, acc[t], 0, 0, 0);
            }
        }
    }

    // epilogue: C/D layout col=lane&15, row=quad*4+r
    #pragma unroll
    for (int t = 0; t < NT; t++) {
        int col = t * 16 + m;
        if ((DOUT % 16 == 0) || (col < DOUT)) {
            float bias = bs[col] + bb[col];
            #pragma unroll
            for (int r = 0; r < 4; r++) {
                int row = base + q * 4 + r;
                if (row < nrows) H[(size_t)row * hstride + col] = f2bf(acc[t][r] + bias);
            }
        }
    }
}

// ---------------- aggregation (wave per node, CSR gather) ----------------

__global__ __launch_bounds__(256) void agg128_kernel(
    const ushortT* __restrict__ H, int hs, ushortT* __restrict__ OUT, int os,
    const float* __restrict__ bg, const int* __restrict__ rowptr,
    const int* __restrict__ colv, const float* __restrict__ dinv,
    float2* __restrict__ STout, int n) {
    int wid = (blockIdx.x * 256 + threadIdx.x) >> 6;
    int lane = threadIdx.x & 63;
    if (wid >= n) return;
    int c = lane * 2;
    float di = dinv[wid];
    unsigned hv = *(const unsigned*)(H + (size_t)wid * hs + c);
    float wself = di * di;
    float a0 = wself * bf2f((unsigned short)hv);
    float a1 = wself * bf2f((unsigned short)(hv >> 16));
    int e0 = rowptr[wid], e1 = rowptr[wid + 1];
    for (int e = e0; e < e1; ++e) {
        int s = colv[e];
        if ((unsigned)s >= (unsigned)n) continue;
        float wgt = dinv[s] * di;
        unsigned v = *(const unsigned*)(H + (size_t)s * hs + c);
        a0 += wgt * bf2f((unsigned short)v);
        a1 += wgt * bf2f((unsigned short)(v >> 16));
    }
    a0 += bg[c];
    a1 += bg[c + 1];
    unsigned r0b = f2bf(a0), r1b = f2bf(a1);
    unsigned outv = r0b | (r1b << 16);
    *(unsigned*)(OUT + (size_t)wid * os + c) = outv;
    // LN stats on the bf16-rounded stored values (what the next layer reads)
    float r0 = bf2f((unsigned short)r0b), r1 = bf2f((unsigned short)r1b);
    float s = r0 + r1, ss = r0 * r0 + r1 * r1;
    #pragma unroll
    for (int d = 1; d < 64; d <<= 1) { s += __shfl_xor(s, d); ss += __shfl_xor(ss, d); }
    if (lane == 0) STout[wid] = make_float2(s, ss);
}

__global__ __launch_bounds__(256) void agg47_kernel(
    const ushortT* __restrict__ H, float* __restrict__ OUT,
    const float* __restrict__ bg, const int* __restrict__ rowptr,
    const int* __restrict__ colv, const float* __restrict__ dinv, int n) {
    int wid = (blockIdx.x * 256 + threadIdx.x) >> 6;
    int lane = threadIdx.x & 63;
    if (wid >= n) return;
    bool act = lane < 47;
    float di = dinv[wid];
    float acc = 0.f;
    if (act) acc = di * di * bf2f(H[(size_t)wid * 47 + lane]);
    int e0 = rowptr[wid], e1 = rowptr[wid + 1];
    for (int e = e0; e < e1; ++e) {
        int s = colv[e];
        if ((unsigned)s >= (unsigned)n) continue;
        float wgt = dinv[s] * di;
        if (act) acc += wgt * bf2f(H[(size_t)s * 47 + lane]);
    }
    if (act) OUT[(size_t)wid * 47 + lane] = acc + bg[lane];
}

// ---------------- launcher ----------------

extern "C" void kernel_launch(void* const* d_in, const int* in_sizes, int n_in,
                              void* d_out, int out_size, void* d_ws, size_t ws_size,
                              hipStream_t stream) {
    const float* x = (const float*)d_in[0];
    const int* ei = (const int*)d_in[1];
    const float* lng0 = (const float*)d_in[2];
    const float* lnb0 = (const float*)d_in[3];
    const float* Ws0 = (const float*)d_in[4];
    const float* bs0 = (const float*)d_in[5];
    const float* Wb0 = (const float*)d_in[6];
    const float* bb0 = (const float*)d_in[7];
    const float* bg0 = (const float*)d_in[8];
    const float* lng1 = (const float*)d_in[9];
    const float* lnb1 = (const float*)d_in[10];
    const float* Ws1 = (const float*)d_in[11];
    const float* bs1 = (const float*)d_in[12];
    const float* Wb1 = (const float*)d_in[13];
    const float* bb1 = (const float*)d_in[14];
    const float* bg1 = (const float*)d_in[15];
    const float* lng2 = (const float*)d_in[16];
    const float* lnb2 = (const float*)d_in[17];
    const float* Ws2 = (const float*)d_in[18];
    const float* bs2 = (const float*)d_in[19];
    const float* Wb2 = (const float*)d_in[20];
    const float* bb2 = (const float*)d_in[21];
    const float* bg2 = (const float*)d_in[22];

    const int N = in_sizes[0] / 128;
    const int E = in_sizes[1] / 2;

    char* wsp = (char*)d_ws;
    size_t off = 0;
    auto alloc = [&](size_t bytes) {
        off = (off + 255) & ~(size_t)255;
        void* p = wsp + off;
        off += bytes;
        return p;
    };
    int* cur = (int*)alloc((size_t)N * 4);
    int* rowptr = (int*)alloc((size_t)(N + 1) * 4);
    int* bsum = (int*)alloc(1024 * 4);
    int* colv = (int*)alloc((size_t)E * 4);
    float* dinvv = (float*)alloc((size_t)N * 4);
    ushortT* hbuf = (ushortT*)alloc((size_t)N * 128 * 2);
    ushortT* a1 = (ushortT*)alloc((size_t)N * 128 * 2);
    ushortT* a2 = (ushortT*)alloc((size_t)N * 128 * 2);
    float2* stx = (float2*)alloc((size_t)N * 8);
    float2* st1 = (float2*)alloc((size_t)N * 8);
    float2* st2 = (float2*)alloc((size_t)N * 8);
    ushortT* Wsb0 = (ushortT*)alloc((size_t)128 * 512 * 2);
    ushortT* Wbb0 = (ushortT*)alloc((size_t)128 * 128 * 2);
    ushortT* Wsb1 = (ushortT*)alloc((size_t)128 * 512 * 2);
    ushortT* Wbb1 = (ushortT*)alloc((size_t)128 * 128 * 2);
    ushortT* Wsb2 = (ushortT*)alloc((size_t)47 * 1536 * 2);
    ushortT* Wbb2 = (ushortT*)alloc((size_t)47 * 384 * 2);
    (void)n_in; (void)out_size; (void)ws_size;

    const int* srcp = ei;
    const int* dstp = ei + E;

    int gN = (N + 255) / 256;
    int gE = (E + 255) / 256;
    int nb = (N + 1023) / 1024;
    int gT = (N + 63) / 64;
    int gW = (N + 3) / 4;

    // weight casts (f32 -> bf16)
    auto cast = [&](const float* in, ushortT* out, int n) {
        int n4 = n / 4;
        cast_f32_bf16<<<(n4 + 255) / 256, 256, 0, stream>>>(in, out, n4);
    };
    cast(Ws0, Wsb0, 128 * 512);
    cast(Wb0, Wbb0, 128 * 128);
    cast(Ws1, Wsb1, 128 * 512);
    cast(Wb1, Wbb1, 128 * 128);
    cast(Ws2, Wsb2, 47 * 1536);
    cast(Wb2, Wbb2, 47 * 384);

    // CSR build + x stats
    zero_ints<<<gN, 256, 0, stream>>>(cur, N);
    hist_kernel<<<gE, 256, 0, stream>>>(dstp, cur, E, N);
    scanA<<<nb, 256, 0, stream>>>(cur, rowptr, bsum, N);
    scanB<<<1, 64, 0, stream>>>(bsum, nb);
    scanC<<<nb, 256, 0, stream>>>(rowptr, bsum, N, E);
    dinv_cur_kernel<<<gN, 256, 0, stream>>>(rowptr, dinvv, cur, N);
    fill_kernel<<<gE, 256, 0, stream>>>(srcp, dstp, cur, colv, E, N);
    stats_f32<<<gW, 256, 0, stream>>>(x, stx, N);

    // layer 1: x(f32) -> h, agg -> a1 (+stats)
    fkan_kernel<1, 128, 1><<<gT, 256, 0, stream>>>(x, 128, x, 128, x, 128,
                                                   stx, stx, stx,
                                                   lng0, lnb0, Wsb0, Wbb0, bs0, bb0, hbuf, 128, N);
    agg128_kernel<<<gW, 256, 0, stream>>>(hbuf, 128, a1, 128, bg0, rowptr, colv, dinvv, st1, N);

    // layer 2: a1(bf16) -> h, agg -> a2 (+stats)
    fkan_kernel<1, 128, 0><<<gT, 256, 0, stream>>>(a1, 128, a1, 128, a1, 128,
                                                   st1, st1, st1,
                                                   lng1, lnb1, Wsb1, Wbb1, bs1, bb1, hbuf, 128, N);
    agg128_kernel<<<gW, 256, 0, stream>>>(hbuf, 128, a2, 128, bg1, rowptr, colv, dinvv, st2, N);

    // layer 3: [x(f32) | a1 | a2] -> h[N,47], agg -> d_out (f32)
    fkan_kernel<3, 47, 1><<<gT, 256, 0, stream>>>(x, 128, a1, 128, a2, 128,
                                                  stx, st1, st2,
                                                  lng2, lnb2, Wsb2, Wbb2, bs2, bb2, hbuf, 47, N);
    agg47_kernel<<<gW, 256, 0, stream>>>(hbuf, (float*)d_out, bg2, rowptr, colv, dinvv, N);
}

// Round 6
// 1150.019 us; speedup vs baseline: 1.1993x; 1.1993x over previous
//
#include <hip/hip_runtime.h>

typedef unsigned short ushortT;
typedef __attribute__((ext_vector_type(8))) short short8;
typedef __attribute__((ext_vector_type(4))) float float4v;

__device__ __forceinline__ float bf2f(unsigned short h) {
    unsigned u = ((unsigned)h) << 16;
    return __builtin_bit_cast(float, u);
}
__device__ __forceinline__ unsigned short f2bf(float f) {
    unsigned u = __builtin_bit_cast(unsigned, f);
    u = u + 0x7fffu + ((u >> 16) & 1u);
    return (unsigned short)(u >> 16);
}

// 8-element row load; f32 flag folds at compile time
__device__ __forceinline__ void loadc8(bool f32, const void* p, size_t off, float o[8]) {
    if (f32) {
        const float* q = (const float*)p + off;
        float4 a = *(const float4*)q;
        float4 b = *(const float4*)(q + 4);
        o[0] = a.x; o[1] = a.y; o[2] = a.z; o[3] = a.w;
        o[4] = b.x; o[5] = b.y; o[6] = b.z; o[7] = b.w;
    } else {
        uint4 v = *(const uint4*)((const ushortT*)p + off);
        unsigned uu[4] = {v.x, v.y, v.z, v.w};
        #pragma unroll
        for (int j = 0; j < 8; j++) o[j] = bf2f((unsigned short)(uu[j >> 1] >> ((j & 1) * 16)));
    }
}

// ---------------- combined weight build: Wc[n][seg*512+g*128+dl | 4*DIN+d] ----------------
// RBF part permuted grid-major so a K-step covers 32 contiguous din for one grid.
__global__ __launch_bounds__(256) void build_wc(const float* __restrict__ Ws, const float* __restrict__ Wb,
                                                ushortT* __restrict__ Wc, int dout, int din) {
    int idx = blockIdx.x * 256 + threadIdx.x;
    int kw = 5 * din;
    if (idx >= dout * kw) return;
    int n = idx / kw, c = idx % kw;
    float v;
    if (c < 4 * din) {
        int seg = c >> 9;
        int rem = c & 511;
        int g = rem >> 7;
        int dl = rem & 127;
        v = Ws[(size_t)n * 4 * din + 4 * (seg * 128 + dl) + g];
    } else {
        v = Wb[(size_t)n * din + (c - 4 * din)];
    }
    Wc[idx] = f2bf(v);
}

// ---------------- per-row LN stats for f32 x (+ optional bf16 mirror) ----------------

__global__ __launch_bounds__(256) void stats_f32(const float* __restrict__ X, float2* __restrict__ ST,
                                                 ushortT* __restrict__ xb, int n) {
    int wid = (blockIdx.x * 256 + threadIdx.x) >> 6;
    int lane = threadIdx.x & 63;
    if (wid >= n) return;
    float2 v = *(const float2*)(X + (size_t)wid * 128 + lane * 2);
    if (xb) {
        unsigned pk = (unsigned)f2bf(v.x) | ((unsigned)f2bf(v.y) << 16);
        *(unsigned*)(xb + (size_t)wid * 128 + lane * 2) = pk;
    }
    float s = v.x + v.y, ss = v.x * v.x + v.y * v.y;
    #pragma unroll
    for (int d = 1; d < 64; d <<= 1) { s += __shfl_xor(s, d); ss += __shfl_xor(ss, d); }
    if (lane == 0) ST[wid] = make_float2(s, ss);
}

// ---------------- CSR build ----------------

__global__ __launch_bounds__(256) void zero_ints(int* p, int n) {
    int i = blockIdx.x * 256 + threadIdx.x;
    if (i < n) p[i] = 0;
}

__global__ __launch_bounds__(256) void hist_kernel(const int* __restrict__ dst, int* __restrict__ cnt, int E, int n) {
    int e = blockIdx.x * 256 + threadIdx.x;
    if (e < E) {
        int d = dst[e];
        if ((unsigned)d < (unsigned)n) atomicAdd(&cnt[d], 1);
    }
}

__device__ __forceinline__ int wave_incl_scan(int v, int lane) {
    #pragma unroll
    for (int d = 1; d < 64; d <<= 1) {
        int o = __shfl_up(v, d);
        if (lane >= d) v += o;
    }
    return v;
}

__global__ __launch_bounds__(256) void scanA(const int* __restrict__ cnt, int* __restrict__ out,
                                             int* __restrict__ bsum, int n) {
    __shared__ int wtot[4];
    int tid = threadIdx.x, blk = blockIdx.x;
    int base = blk * 1024 + tid * 4;
    int e[4];
    #pragma unroll
    for (int j = 0; j < 4; j++) { int idx = base + j; e[j] = (idx < n) ? cnt[idx] : 0; }
    int s = e[0] + e[1] + e[2] + e[3];
    int lane = tid & 63, w = tid >> 6;
    int incl = wave_incl_scan(s, lane);
    if (lane == 63) wtot[w] = incl;
    __syncthreads();
    int woff = 0;
    for (int i = 0; i < w; i++) woff += wtot[i];
    int run = woff + incl - s;
    #pragma unroll
    for (int j = 0; j < 4; j++) { int idx = base + j; if (idx < n) out[idx] = run; run += e[j]; }
    if (tid == 0) bsum[blk] = wtot[0] + wtot[1] + wtot[2] + wtot[3];
}

__global__ __launch_bounds__(64) void scanB(int* bsum, int nb) {
    int lane = threadIdx.x;
    int carry = 0;
    for (int base = 0; base < nb; base += 64) {
        int i = base + lane;
        int v = (i < nb) ? bsum[i] : 0;
        int incl = wave_incl_scan(v, lane);
        if (i < nb) bsum[i] = carry + incl - v;
        carry += __shfl(incl, 63);
    }
}

__global__ __launch_bounds__(256) void scanC(int* __restrict__ out, const int* __restrict__ bsum, int n, int E) {
    int blk = blockIdx.x, tid = threadIdx.x;
    int off = bsum[blk];
    int base = blk * 1024 + tid * 4;
    #pragma unroll
    for (int j = 0; j < 4; j++) { int idx = base + j; if (idx < n) out[idx] += off; }
    if (blk == 0 && tid == 0) out[n] = E;
}

__global__ __launch_bounds__(256) void dinv_cur_kernel(const int* __restrict__ rowptr, float* __restrict__ dinv,
                                                       int* __restrict__ cur, int n) {
    int i = blockIdx.x * 256 + threadIdx.x;
    if (i < n) {
        int deg = rowptr[i + 1] - rowptr[i] + 1;  // +1 self loop
        dinv[i] = rsqrtf((float)max(deg, 1));
        cur[i] = rowptr[i];
    }
}

__global__ __launch_bounds__(256) void fill_kernel(const int* __restrict__ src, const int* __restrict__ dst,
                                                   int* __restrict__ cur, int* __restrict__ colv, int E, int n) {
    int e = blockIdx.x * 256 + threadIdx.x;
    if (e < E) {
        int d = dst[e];
        if ((unsigned)d < (unsigned)n) {
            int p = atomicAdd(&cur[d], 1);
            colv[p] = src[e];
        }
    }
}

// ---------------- fused FastKAN transform ----------------
// No LDS. Wave = 16 output cols span handled via NT tiles; 2 row-groups (16+16 rows).
// K-order matches Wc: [seg][grid][din] for RBF, then [seg][din] for SiLU.
template <int NSEG, int DOUT, int F32MASK>
__global__ __launch_bounds__(256) void fkan_kernel(
    const void* __restrict__ X0, int s0,
    const void* __restrict__ X1, int s1,
    const void* __restrict__ X2, int s2,
    const float2* __restrict__ ST0, const float2* __restrict__ ST1, const float2* __restrict__ ST2,
    const float* __restrict__ lng, const float* __restrict__ lnb,
    const ushortT* __restrict__ Wc,
    const float* __restrict__ bs, const float* __restrict__ bb,
    ushortT* __restrict__ H, int hstride, int nrows) {
    constexpr int DIN = NSEG * 128;
    constexpr int KW = 5 * DIN;
    constexpr int NT = (DOUT + 15) / 16;
    int tid = threadIdx.x;
    int w = tid >> 6, lane = tid & 63;
    int m = lane & 15, q = lane >> 4;
    int baseA = blockIdx.x * 128 + w * 16;
    int baseB = baseA + 64;
    int rA = min(baseA + m, nrows - 1);
    int rB = min(baseB + m, nrows - 1);

    float muA, scA, muB, scB;
    {
        float2 st = ST0[rA]; float sum = st.x, ssq = st.y;
        if (NSEG == 3) { float2 t1 = ST1[rA]; sum += t1.x; ssq += t1.y; float2 t2 = ST2[rA]; sum += t2.x; ssq += t2.y; }
        muA = sum * (1.0f / DIN);
        float var = ssq * (1.0f / DIN) - muA * muA;
        scA = rsqrtf(fmaxf(var, 0.0f) + 1e-5f);
    }
    {
        float2 st = ST0[rB]; float sum = st.x, ssq = st.y;
        if (NSEG == 3) { float2 t1 = ST1[rB]; sum += t1.x; ssq += t1.y; float2 t2 = ST2[rB]; sum += t2.x; ssq += t2.y; }
        muB = sum * (1.0f / DIN);
        float var = ssq * (1.0f / DIN) - muB * muB;
        scB = rsqrtf(fmaxf(var, 0.0f) + 1e-5f);
    }

    float4v acc[NT][2];
    #pragma unroll
    for (int t = 0; t < NT; t++) {
        acc[t][0] = (float4v){0.f, 0.f, 0.f, 0.f};
        acc[t][1] = (float4v){0.f, 0.f, 0.f, 0.f};
    }

    const float G[4] = {-2.f, -2.f / 3.f, 2.f / 3.f, 2.f};

    // ---- RBF region: per segment, 4 supersteps of 32 din; each superstep = 4 grid K-steps ----
    #pragma unroll
    for (int seg = 0; seg < NSEG; seg++) {
        const void* Xp = (seg == 0) ? X0 : (seg == 1) ? X1 : X2;
        int str = (seg == 0) ? s0 : (seg == 1) ? s1 : s2;
        bool f32 = ((F32MASK >> seg) & 1) != 0;
        #pragma unroll
        for (int i = 0; i < 4; i++) {
            int d0 = i * 32 + q * 8;  // this lane's 8 din within segment
            float xa[8], xb8[8];
            loadc8(f32, Xp, (size_t)rA * str + d0, xa);
            loadc8(f32, Xp, (size_t)rB * str + d0, xb8);
            float4 gv0 = *(const float4*)(lng + seg * 128 + d0);
            float4 gv1 = *(const float4*)(lng + seg * 128 + d0 + 4);
            float4 bv0 = *(const float4*)(lnb + seg * 128 + d0);
            float4 bv1 = *(const float4*)(lnb + seg * 128 + d0 + 4);
            float gvs[8] = {gv0.x, gv0.y, gv0.z, gv0.w, gv1.x, gv1.y, gv1.z, gv1.w};
            float bvs[8] = {bv0.x, bv0.y, bv0.z, bv0.w, bv1.x, bv1.y, bv1.z, bv1.w};
            float za[8], zb[8];
            #pragma unroll
            for (int j = 0; j < 8; j++) {
                za[j] = (xa[j] - muA) * scA * gvs[j] + bvs[j];
                zb[j] = (xb8[j] - muB) * scB * gvs[j] + bvs[j];
            }
            #pragma unroll
            for (int g = 0; g < 4; g++) {
                short8 afa, afb;
                #pragma unroll
                for (int j = 0; j < 8; j++) {
                    float da = (za[j] - G[g]) * 0.75f;  // 1/DENOM = 3/4
                    afa[j] = (short)f2bf(__expf(-da * da));
                    float db = (zb[j] - G[g]) * 0.75f;
                    afb[j] = (short)f2bf(__expf(-db * db));
                }
                int kbase = seg * 512 + g * 128 + i * 32;
                #pragma unroll
                for (int t = 0; t < NT; t++) {
                    int n = t * 16 + m;
                    short8 bfr = (short8){0, 0, 0, 0, 0, 0, 0, 0};
                    if ((DOUT % 16 == 0) || (n < DOUT))
                        bfr = *(const short8*)(Wc + (size_t)n * KW + kbase + q * 8);
                    acc[t][0] = __builtin_amdgcn_mfma_f32_16x16x32_bf16(afa, bfr, acc[t][0], 0, 0, 0);
                    acc[t][1] = __builtin_amdgcn_mfma_f32_16x16x32_bf16(afb, bfr, acc[t][1], 0, 0, 0);
                }
            }
        }
    }

    // ---- SiLU region: per segment, 4 K-steps of 32 din ----
    #pragma unroll
    for (int seg = 0; seg < NSEG; seg++) {
        const void* Xp = (seg == 0) ? X0 : (seg == 1) ? X1 : X2;
        int str = (seg == 0) ? s0 : (seg == 1) ? s1 : s2;
        bool f32 = ((F32MASK >> seg) & 1) != 0;
        #pragma unroll
        for (int i = 0; i < 4; i++) {
            int c = i * 32 + q * 8;
            float xa[8], xb8[8];
            loadc8(f32, Xp, (size_t)rA * str + c, xa);
            loadc8(f32, Xp, (size_t)rB * str + c, xb8);
            short8 afa, afb;
            #pragma unroll
            for (int j = 0; j < 8; j++) {
                float sa = 1.0f / (1.0f + __expf(-xa[j]));
                afa[j] = (short)f2bf(xa[j] * sa);
                float sb = 1.0f / (1.0f + __expf(-xb8[j]));
                afb[j] = (short)f2bf(xb8[j] * sb);
            }
            int kbase = 4 * DIN + seg * 128 + i * 32;
            #pragma unroll
            for (int t = 0; t < NT; t++) {
                int n = t * 16 + m;
                short8 bfr = (short8){0, 0, 0, 0, 0, 0, 0, 0};
                if ((DOUT % 16 == 0) || (n < DOUT))
                    bfr = *(const short8*)(Wc + (size_t)n * KW + kbase + q * 8);
                acc[t][0] = __builtin_amdgcn_mfma_f32_16x16x32_bf16(afa, bfr, acc[t][0], 0, 0, 0);
                acc[t][1] = __builtin_amdgcn_mfma_f32_16x16x32_bf16(afb, bfr, acc[t][1], 0, 0, 0);
            }
        }
    }

    // epilogue: C/D layout col=lane&15, row=quad*4+r
    #pragma unroll
    for (int t = 0; t < NT; t++) {
        int col = t * 16 + m;
        if ((DOUT % 16 == 0) || (col < DOUT)) {
            float bias = bs[col] + bb[col];
            #pragma unroll
            for (int r = 0; r < 4; r++) {
                int rowA = baseA + q * 4 + r;
                if (rowA < nrows) H[(size_t)rowA * hstride + col] = f2bf(acc[t][0][r] + bias);
                int rowB = baseB + q * 4 + r;
                if (rowB < nrows) H[(size_t)rowB * hstride + col] = f2bf(acc[t][1][r] + bias);
            }
        }
    }
}

// ---------------- aggregation (wave per node, CSR gather) ----------------

__global__ __launch_bounds__(256) void agg128_kernel(
    const ushortT* __restrict__ H, int hs, ushortT* __restrict__ OUT, int os,
    const float* __restrict__ bg, const int* __restrict__ rowptr,
    const int* __restrict__ colv, const float* __restrict__ dinv,
    float2* __restrict__ STout, int n) {
    int wid = (blockIdx.x * 256 + threadIdx.x) >> 6;
    int lane = threadIdx.x & 63;
    if (wid >= n) return;
    int c = lane * 2;
    float di = dinv[wid];
    unsigned hv = *(const unsigned*)(H + (size_t)wid * hs + c);
    float wself = di * di;
    float a0 = wself * bf2f((unsigned short)hv);
    float a1 = wself * bf2f((unsigned short)(hv >> 16));
    int e0 = rowptr[wid], e1 = rowptr[wid + 1];
    for (int e = e0; e < e1; ++e) {
        int s = colv[e];
        if ((unsigned)s >= (unsigned)n) continue;
        float wgt = dinv[s] * di;
        unsigned v = *(const unsigned*)(H + (size_t)s * hs + c);
        a0 += wgt * bf2f((unsigned short)v);
        a1 += wgt * bf2f((unsigned short)(v >> 16));
    }
    a0 += bg[c];
    a1 += bg[c + 1];
    unsigned r0b = f2bf(a0), r1b = f2bf(a1);
    *(unsigned*)(OUT + (size_t)wid * os + c) = r0b | (r1b << 16);
    // LN stats on the bf16-rounded stored values (what the next layer reads)
    float r0 = bf2f((unsigned short)r0b), r1 = bf2f((unsigned short)r1b);
    float s = r0 + r1, ss = r0 * r0 + r1 * r1;
    #pragma unroll
    for (int d = 1; d < 64; d <<= 1) { s += __shfl_xor(s, d); ss += __shfl_xor(ss, d); }
    if (lane == 0) STout[wid] = make_float2(s, ss);
}

__global__ __launch_bounds__(256) void agg47_kernel(
    const ushortT* __restrict__ H, float* __restrict__ OUT,
    const float* __restrict__ bg, const int* __restrict__ rowptr,
    const int* __restrict__ colv, const float* __restrict__ dinv, int n) {
    int wid = (blockIdx.x * 256 + threadIdx.x) >> 6;
    int lane = threadIdx.x & 63;
    if (wid >= n) return;
    bool act = lane < 47;
    float di = dinv[wid];
    float acc = 0.f;
    if (act) acc = di * di * bf2f(H[(size_t)wid * 47 + lane]);
    int e0 = rowptr[wid], e1 = rowptr[wid + 1];
    for (int e = e0; e < e1; ++e) {
        int s = colv[e];
        if ((unsigned)s >= (unsigned)n) continue;
        float wgt = dinv[s] * di;
        if (act) acc += wgt * bf2f(H[(size_t)s * 47 + lane]);
    }
    if (act) OUT[(size_t)wid * 47 + lane] = acc + bg[lane];
}

// ---------------- launcher ----------------

extern "C" void kernel_launch(void* const* d_in, const int* in_sizes, int n_in,
                              void* d_out, int out_size, void* d_ws, size_t ws_size,
                              hipStream_t stream) {
    const float* x = (const float*)d_in[0];
    const int* ei = (const int*)d_in[1];
    const float* lng0 = (const float*)d_in[2];
    const float* lnb0 = (const float*)d_in[3];
    const float* Ws0 = (const float*)d_in[4];
    const float* bs0 = (const float*)d_in[5];
    const float* Wb0 = (const float*)d_in[6];
    const float* bb0 = (const float*)d_in[7];
    const float* bg0 = (const float*)d_in[8];
    const float* lng1 = (const float*)d_in[9];
    const float* lnb1 = (const float*)d_in[10];
    const float* Ws1 = (const float*)d_in[11];
    const float* bs1 = (const float*)d_in[12];
    const float* Wb1 = (const float*)d_in[13];
    const float* bb1 = (const float*)d_in[14];
    const float* bg1 = (const float*)d_in[15];
    const float* lng2 = (const float*)d_in[16];
    const float* lnb2 = (const float*)d_in[17];
    const float* Ws2 = (const float*)d_in[18];
    const float* bs2 = (const float*)d_in[19];
    const float* Wb2 = (const float*)d_in[20];
    const float* bb2 = (const float*)d_in[21];
    const float* bg2 = (const float*)d_in[22];

    const int N = in_sizes[0] / 128;
    const int E = in_sizes[1] / 2;

    char* wsp = (char*)d_ws;
    size_t off = 0;
    auto alloc = [&](size_t bytes) {
        off = (off + 255) & ~(size_t)255;
        void* p = wsp + off;
        off += bytes;
        return p;
    };
    int* cur = (int*)alloc((size_t)N * 4);
    int* rowptr = (int*)alloc((size_t)(N + 1) * 4);
    int* bsum = (int*)alloc(1024 * 4);
    int* colv = (int*)alloc((size_t)E * 4);
    float* dinvv = (float*)alloc((size_t)N * 4);
    ushortT* hbuf = (ushortT*)alloc((size_t)N * 128 * 2);
    ushortT* a1 = (ushortT*)alloc((size_t)N * 128 * 2);
    ushortT* a2 = (ushortT*)alloc((size_t)N * 128 * 2);
    float2* stx = (float2*)alloc((size_t)N * 8);
    float2* st1 = (float2*)alloc((size_t)N * 8);
    float2* st2 = (float2*)alloc((size_t)N * 8);
    ushortT* Wc0 = (ushortT*)alloc((size_t)128 * 640 * 2);
    ushortT* Wc1 = (ushortT*)alloc((size_t)128 * 640 * 2);
    ushortT* Wc2 = (ushortT*)alloc((size_t)47 * 1920 * 2);
    size_t off_base = off;
    ushortT* xb = (ushortT*)alloc((size_t)N * 128 * 2);  // bf16 mirror of x
    bool fits = (off <= ws_size);
    if (!fits) off = off_base;  // xb unused
    (void)n_in; (void)out_size;

    const int* srcp = ei;
    const int* dstp = ei + E;

    int gN = (N + 255) / 256;
    int gE = (E + 255) / 256;
    int nb = (N + 1023) / 1024;
    int gF = (N + 127) / 128;     // fkan blocks (128 rows each)
    int gW = (N + 3) / 4;         // wave-per-node blocks

    // combined bf16 weights (grid-major RBF + silu)
    build_wc<<<(128 * 640 + 255) / 256, 256, 0, stream>>>(Ws0, Wb0, Wc0, 128, 128);
    build_wc<<<(128 * 640 + 255) / 256, 256, 0, stream>>>(Ws1, Wb1, Wc1, 128, 128);
    build_wc<<<(47 * 1920 + 255) / 256, 256, 0, stream>>>(Ws2, Wb2, Wc2, 47, 384);

    // CSR build + x stats (+ bf16 mirror)
    zero_ints<<<gN, 256, 0, stream>>>(cur, N);
    hist_kernel<<<gE, 256, 0, stream>>>(dstp, cur, E, N);
    scanA<<<nb, 256, 0, stream>>>(cur, rowptr, bsum, N);
    scanB<<<1, 64, 0, stream>>>(bsum, nb);
    scanC<<<nb, 256, 0, stream>>>(rowptr, bsum, N, E);
    dinv_cur_kernel<<<gN, 256, 0, stream>>>(rowptr, dinvv, cur, N);
    fill_kernel<<<gE, 256, 0, stream>>>(srcp, dstp, cur, colv, E, N);
    stats_f32<<<gW, 256, 0, stream>>>(x, stx, fits ? xb : nullptr, N);

    // layer 1
    if (fits)
        fkan_kernel<1, 128, 0><<<gF, 256, 0, stream>>>(xb, 128, xb, 128, xb, 128, stx, stx, stx,
                                                       lng0, lnb0, Wc0, bs0, bb0, hbuf, 128, N);
    else
        fkan_kernel<1, 128, 1><<<gF, 256, 0, stream>>>(x, 128, x, 128, x, 128, stx, stx, stx,
                                                       lng0, lnb0, Wc0, bs0, bb0, hbuf, 128, N);
    agg128_kernel<<<gW, 256, 0, stream>>>(hbuf, 128, a1, 128, bg0, rowptr, colv, dinvv, st1, N);

    // layer 2
    fkan_kernel<1, 128, 0><<<gF, 256, 0, stream>>>(a1, 128, a1, 128, a1, 128, st1, st1, st1,
                                                   lng1, lnb1, Wc1, bs1, bb1, hbuf, 128, N);
    agg128_kernel<<<gW, 256, 0, stream>>>(hbuf, 128, a2, 128, bg1, rowptr, colv, dinvv, st2, N);

    // layer 3
    if (fits)
        fkan_kernel<3, 47, 0><<<gF, 256, 0, stream>>>(xb, 128, a1, 128, a2, 128, stx, st1, st2,
                                                      lng2, lnb2, Wc2, bs2, bb2, hbuf, 47, N);
    else
        fkan_kernel<3, 47, 1><<<gF, 256, 0, stream>>>(x, 128, a1, 128, a2, 128, stx, st1, st2,
                                                      lng2, lnb2, Wc2, bs2, bb2, hbuf, 47, N);
    agg47_kernel<<<gW, 256, 0, stream>>>(hbuf, (float*)d_out, bg2, rowptr, colv, dinvv, N);
}

// Round 7
// 869.764 us; speedup vs baseline: 1.5857x; 1.3222x over previous
//
#include <hip/hip_runtime.h>

typedef unsigned short ushortT;
typedef __attribute__((ext_vector_type(8))) short short8;
typedef __attribute__((ext_vector_type(4))) float float4v;

__device__ __forceinline__ float bf2f(unsigned short h) {
    unsigned u = ((unsigned)h) << 16;
    return __builtin_bit_cast(float, u);
}
__device__ __forceinline__ unsigned short f2bf(float f) {
    unsigned u = __builtin_bit_cast(unsigned, f);
    u = u + 0x7fffu + ((u >> 16) & 1u);
    return (unsigned short)(u >> 16);
}
__device__ __forceinline__ void unpack_add(uint4 v, float a[8]) {
    a[0] += bf2f((ushortT)v.x); a[1] += bf2f((ushortT)(v.x >> 16));
    a[2] += bf2f((ushortT)v.y); a[3] += bf2f((ushortT)(v.y >> 16));
    a[4] += bf2f((ushortT)v.z); a[5] += bf2f((ushortT)(v.z >> 16));
    a[6] += bf2f((ushortT)v.w); a[7] += bf2f((ushortT)(v.w >> 16));
}

// 8-element row load; f32 flag folds at compile time
__device__ __forceinline__ void loadc8(bool f32, const void* p, size_t off, float o[8]) {
    if (f32) {
        const float* q = (const float*)p + off;
        float4 a = *(const float4*)q;
        float4 b = *(const float4*)(q + 4);
        o[0] = a.x; o[1] = a.y; o[2] = a.z; o[3] = a.w;
        o[4] = b.x; o[5] = b.y; o[6] = b.z; o[7] = b.w;
    } else {
        uint4 v = *(const uint4*)((const ushortT*)p + off);
        unsigned uu[4] = {v.x, v.y, v.z, v.w};
        #pragma unroll
        for (int j = 0; j < 8; j++) o[j] = bf2f((unsigned short)(uu[j >> 1] >> ((j & 1) * 16)));
    }
}

// ---------------- combined weight build: Wc[n][seg*512+g*128+dl | 4*DIN+d] ----------------
__global__ __launch_bounds__(256) void build_wc(const float* __restrict__ Ws, const float* __restrict__ Wb,
                                                ushortT* __restrict__ Wc, int dout, int din) {
    int idx = blockIdx.x * 256 + threadIdx.x;
    int kw = 5 * din;
    if (idx >= dout * kw) return;
    int n = idx / kw, c = idx % kw;
    float v;
    if (c < 4 * din) {
        int seg = c >> 9;
        int rem = c & 511;
        int g = rem >> 7;
        int dl = rem & 127;
        v = Ws[(size_t)n * 4 * din + 4 * (seg * 128 + dl) + g];
    } else {
        v = Wb[(size_t)n * din + (c - 4 * din)];
    }
    Wc[idx] = f2bf(v);
}

// ---------------- per-row LN stats for f32 x (+ optional bf16 mirror) ----------------

__global__ __launch_bounds__(256) void stats_f32(const float* __restrict__ X, float2* __restrict__ ST,
                                                 ushortT* __restrict__ xb, int n) {
    int wid = (blockIdx.x * 256 + threadIdx.x) >> 6;
    int lane = threadIdx.x & 63;
    if (wid >= n) return;
    float2 v = *(const float2*)(X + (size_t)wid * 128 + lane * 2);
    if (xb) {
        unsigned pk = (unsigned)f2bf(v.x) | ((unsigned)f2bf(v.y) << 16);
        *(unsigned*)(xb + (size_t)wid * 128 + lane * 2) = pk;
    }
    float s = v.x + v.y, ss = v.x * v.x + v.y * v.y;
    #pragma unroll
    for (int d = 1; d < 64; d <<= 1) { s += __shfl_xor(s, d); ss += __shfl_xor(ss, d); }
    if (lane == 0) ST[wid] = make_float2(s, ss);
}

// ---------------- CSR build ----------------

__global__ __launch_bounds__(256) void zero_ints(int* p, int n) {
    int i = blockIdx.x * 256 + threadIdx.x;
    if (i < n) p[i] = 0;
}

__global__ __launch_bounds__(256) void hist_kernel(const int* __restrict__ dst, int* __restrict__ cnt, int E, int n) {
    int e = blockIdx.x * 256 + threadIdx.x;
    if (e < E) {
        int d = dst[e];
        if ((unsigned)d < (unsigned)n) atomicAdd(&cnt[d], 1);
    }
}

__device__ __forceinline__ int wave_incl_scan(int v, int lane) {
    #pragma unroll
    for (int d = 1; d < 64; d <<= 1) {
        int o = __shfl_up(v, d);
        if (lane >= d) v += o;
    }
    return v;
}

__global__ __launch_bounds__(256) void scanA(const int* __restrict__ cnt, int* __restrict__ out,
                                             int* __restrict__ bsum, int n) {
    __shared__ int wtot[4];
    int tid = threadIdx.x, blk = blockIdx.x;
    int base = blk * 1024 + tid * 4;
    int e[4];
    #pragma unroll
    for (int j = 0; j < 4; j++) { int idx = base + j; e[j] = (idx < n) ? cnt[idx] : 0; }
    int s = e[0] + e[1] + e[2] + e[3];
    int lane = tid & 63, w = tid >> 6;
    int incl = wave_incl_scan(s, lane);
    if (lane == 63) wtot[w] = incl;
    __syncthreads();
    int woff = 0;
    for (int i = 0; i < w; i++) woff += wtot[i];
    int run = woff + incl - s;
    #pragma unroll
    for (int j = 0; j < 4; j++) { int idx = base + j; if (idx < n) out[idx] = run; run += e[j]; }
    if (tid == 0) bsum[blk] = wtot[0] + wtot[1] + wtot[2] + wtot[3];
}

__global__ __launch_bounds__(64) void scanB(int* bsum, int nb) {
    int lane = threadIdx.x;
    int carry = 0;
    for (int base = 0; base < nb; base += 64) {
        int i = base + lane;
        int v = (i < nb) ? bsum[i] : 0;
        int incl = wave_incl_scan(v, lane);
        if (i < nb) bsum[i] = carry + incl - v;
        carry += __shfl(incl, 63);
    }
}

__global__ __launch_bounds__(256) void scanC(int* __restrict__ out, const int* __restrict__ bsum, int n, int E) {
    int blk = blockIdx.x, tid = threadIdx.x;
    int off = bsum[blk];
    int base = blk * 1024 + tid * 4;
    #pragma unroll
    for (int j = 0; j < 4; j++) { int idx = base + j; if (idx < n) out[idx] += off; }
    if (blk == 0 && tid == 0) out[n] = E;
}

__global__ __launch_bounds__(256) void dinv_cur_kernel(const int* __restrict__ rowptr, float* __restrict__ dinv,
                                                       int* __restrict__ cur, int n) {
    int i = blockIdx.x * 256 + threadIdx.x;
    if (i < n) {
        int deg = rowptr[i + 1] - rowptr[i] + 1;  // +1 self loop
        dinv[i] = rsqrtf((float)max(deg, 1));
        cur[i] = rowptr[i];
    }
}

__global__ __launch_bounds__(256) void fill_kernel(const int* __restrict__ src, const int* __restrict__ dst,
                                                   int* __restrict__ cur, int* __restrict__ colv, int E, int n) {
    int e = blockIdx.x * 256 + threadIdx.x;
    if (e < E) {
        int d = dst[e];
        if ((unsigned)d < (unsigned)n) {
            int p = atomicAdd(&cur[d], 1);
            colv[p] = src[e];
        }
    }
}

// ---------------- fused FastKAN transform ----------------
// No LDS. 2 row-groups (16+16 rows) per wave. K-order matches Wc.
// Output rows are PRE-SCALED by dinv[row] (for the gather that follows).
template <int NSEG, int DOUT, int F32MASK>
__global__ __launch_bounds__(256) void fkan_kernel(
    const void* __restrict__ X0, int s0,
    const void* __restrict__ X1, int s1,
    const void* __restrict__ X2, int s2,
    const float2* __restrict__ ST0, const float2* __restrict__ ST1, const float2* __restrict__ ST2,
    const float* __restrict__ lng, const float* __restrict__ lnb,
    const ushortT* __restrict__ Wc,
    const float* __restrict__ bs, const float* __restrict__ bb,
    const float* __restrict__ dinv,
    ushortT* __restrict__ H, int hstride, int nrows) {
    constexpr int DIN = NSEG * 128;
    constexpr int KW = 5 * DIN;
    constexpr int NT = (DOUT + 15) / 16;
    int tid = threadIdx.x;
    int w = tid >> 6, lane = tid & 63;
    int m = lane & 15, q = lane >> 4;
    int baseA = blockIdx.x * 128 + w * 16;
    int baseB = baseA + 64;
    int rA = min(baseA + m, nrows - 1);
    int rB = min(baseB + m, nrows - 1);

    float muA, scA, muB, scB;
    {
        float2 st = ST0[rA]; float sum = st.x, ssq = st.y;
        if (NSEG == 3) { float2 t1 = ST1[rA]; sum += t1.x; ssq += t1.y; float2 t2 = ST2[rA]; sum += t2.x; ssq += t2.y; }
        muA = sum * (1.0f / DIN);
        float var = ssq * (1.0f / DIN) - muA * muA;
        scA = rsqrtf(fmaxf(var, 0.0f) + 1e-5f);
    }
    {
        float2 st = ST0[rB]; float sum = st.x, ssq = st.y;
        if (NSEG == 3) { float2 t1 = ST1[rB]; sum += t1.x; ssq += t1.y; float2 t2 = ST2[rB]; sum += t2.x; ssq += t2.y; }
        muB = sum * (1.0f / DIN);
        float var = ssq * (1.0f / DIN) - muB * muB;
        scB = rsqrtf(fmaxf(var, 0.0f) + 1e-5f);
    }

    float4v acc[NT][2];
    #pragma unroll
    for (int t = 0; t < NT; t++) {
        acc[t][0] = (float4v){0.f, 0.f, 0.f, 0.f};
        acc[t][1] = (float4v){0.f, 0.f, 0.f, 0.f};
    }

    const float G[4] = {-2.f, -2.f / 3.f, 2.f / 3.f, 2.f};

    // ---- RBF region ----
    #pragma unroll
    for (int seg = 0; seg < NSEG; seg++) {
        const void* Xp = (seg == 0) ? X0 : (seg == 1) ? X1 : X2;
        int str = (seg == 0) ? s0 : (seg == 1) ? s1 : s2;
        bool f32 = ((F32MASK >> seg) & 1) != 0;
        #pragma unroll
        for (int i = 0; i < 4; i++) {
            int d0 = i * 32 + q * 8;
            float xa[8], xb8[8];
            loadc8(f32, Xp, (size_t)rA * str + d0, xa);
            loadc8(f32, Xp, (size_t)rB * str + d0, xb8);
            float4 gv0 = *(const float4*)(lng + seg * 128 + d0);
            float4 gv1 = *(const float4*)(lng + seg * 128 + d0 + 4);
            float4 bv0 = *(const float4*)(lnb + seg * 128 + d0);
            float4 bv1 = *(const float4*)(lnb + seg * 128 + d0 + 4);
            float gvs[8] = {gv0.x, gv0.y, gv0.z, gv0.w, gv1.x, gv1.y, gv1.z, gv1.w};
            float bvs[8] = {bv0.x, bv0.y, bv0.z, bv0.w, bv1.x, bv1.y, bv1.z, bv1.w};
            float za[8], zb[8];
            #pragma unroll
            for (int j = 0; j < 8; j++) {
                za[j] = (xa[j] - muA) * scA * gvs[j] + bvs[j];
                zb[j] = (xb8[j] - muB) * scB * gvs[j] + bvs[j];
            }
            #pragma unroll
            for (int g = 0; g < 4; g++) {
                short8 afa, afb;
                #pragma unroll
                for (int j = 0; j < 8; j++) {
                    float da = (za[j] - G[g]) * 0.75f;
                    afa[j] = (short)f2bf(__expf(-da * da));
                    float db = (zb[j] - G[g]) * 0.75f;
                    afb[j] = (short)f2bf(__expf(-db * db));
                }
                int kbase = seg * 512 + g * 128 + i * 32;
                #pragma unroll
                for (int t = 0; t < NT; t++) {
                    int n = t * 16 + m;
                    short8 bfr = (short8){0, 0, 0, 0, 0, 0, 0, 0};
                    if ((DOUT % 16 == 0) || (n < DOUT))
                        bfr = *(const short8*)(Wc + (size_t)n * KW + kbase + q * 8);
                    acc[t][0] = __builtin_amdgcn_mfma_f32_16x16x32_bf16(afa, bfr, acc[t][0], 0, 0, 0);
                    acc[t][1] = __builtin_amdgcn_mfma_f32_16x16x32_bf16(afb, bfr, acc[t][1], 0, 0, 0);
                }
            }
        }
    }

    // ---- SiLU region ----
    #pragma unroll
    for (int seg = 0; seg < NSEG; seg++) {
        const void* Xp = (seg == 0) ? X0 : (seg == 1) ? X1 : X2;
        int str = (seg == 0) ? s0 : (seg == 1) ? s1 : s2;
        bool f32 = ((F32MASK >> seg) & 1) != 0;
        #pragma unroll
        for (int i = 0; i < 4; i++) {
            int c = i * 32 + q * 8;
            float xa[8], xb8[8];
            loadc8(f32, Xp, (size_t)rA * str + c, xa);
            loadc8(f32, Xp, (size_t)rB * str + c, xb8);
            short8 afa, afb;
            #pragma unroll
            for (int j = 0; j < 8; j++) {
                float sa = 1.0f / (1.0f + __expf(-xa[j]));
                afa[j] = (short)f2bf(xa[j] * sa);
                float sb = 1.0f / (1.0f + __expf(-xb8[j]));
                afb[j] = (short)f2bf(xb8[j] * sb);
            }
            int kbase = 4 * DIN + seg * 128 + i * 32;
            #pragma unroll
            for (int t = 0; t < NT; t++) {
                int n = t * 16 + m;
                short8 bfr = (short8){0, 0, 0, 0, 0, 0, 0, 0};
                if ((DOUT % 16 == 0) || (n < DOUT))
                    bfr = *(const short8*)(Wc + (size_t)n * KW + kbase + q * 8);
                acc[t][0] = __builtin_amdgcn_mfma_f32_16x16x32_bf16(afa, bfr, acc[t][0], 0, 0, 0);
                acc[t][1] = __builtin_amdgcn_mfma_f32_16x16x32_bf16(afb, bfr, acc[t][1], 0, 0, 0);
            }
        }
    }

    // epilogue: C/D layout col=lane&15, row=quad*4+r ; store h*dinv[row]
    float dA[4], dB[4];
    #pragma unroll
    for (int r = 0; r < 4; r++) {
        int rowA = baseA + q * 4 + r;
        dA[r] = (rowA < nrows) ? dinv[rowA] : 0.f;
        int rowB = baseB + q * 4 + r;
        dB[r] = (rowB < nrows) ? dinv[rowB] : 0.f;
    }
    #pragma unroll
    for (int t = 0; t < NT; t++) {
        int col = t * 16 + m;
        if ((DOUT % 16 == 0) || (col < DOUT)) {
            float bias = bs[col] + bb[col];
            #pragma unroll
            for (int r = 0; r < 4; r++) {
                int rowA = baseA + q * 4 + r;
                if (rowA < nrows) H[(size_t)rowA * hstride + col] = f2bf((acc[t][0][r] + bias) * dA[r]);
                int rowB = baseB + q * 4 + r;
                if (rowB < nrows) H[(size_t)rowB * hstride + col] = f2bf((acc[t][1][r] + bias) * dB[r]);
            }
        }
    }
}

// ---------------- aggregation: wave per node, 4 edges in flight ----------------
// H is pre-scaled by dinv[src]. out = dinv[wid]*(H[wid] + sum_nbr H[s]) + bg.

__global__ __launch_bounds__(256) void agg128_kernel(
    const ushortT* __restrict__ H, ushortT* __restrict__ OUT,
    const float* __restrict__ bg, const int* __restrict__ rowptr,
    const int* __restrict__ colv, const float* __restrict__ dinv,
    float2* __restrict__ STout, int n) {
    int wid = (blockIdx.x * 256 + threadIdx.x) >> 6;
    int lane = threadIdx.x & 63;
    if (wid >= n) return;
    int g = lane >> 4, t = lane & 15;
    float di = dinv[wid];
    float a[8] = {0.f, 0.f, 0.f, 0.f, 0.f, 0.f, 0.f, 0.f};
    if (g == 0) unpack_add(*(const uint4*)(H + (size_t)wid * 128 + t * 8), a);  // self
    int e0 = rowptr[wid], e1 = rowptr[wid + 1];
    for (int e = e0 + g; e < e1; e += 4) {
        int s = colv[e];
        unpack_add(*(const uint4*)(H + (size_t)s * 128 + t * 8), a);
    }
    #pragma unroll
    for (int j = 0; j < 8; j++) {
        a[j] += __shfl_xor(a[j], 16);
        a[j] += __shfl_xor(a[j], 32);
    }
    if (g == 0) {
        float4 b0 = *(const float4*)(bg + t * 8);
        float4 b1 = *(const float4*)(bg + t * 8 + 4);
        float bgs[8] = {b0.x, b0.y, b0.z, b0.w, b1.x, b1.y, b1.z, b1.w};
        unsigned rb[8];
        float s = 0.f, ss = 0.f;
        #pragma unroll
        for (int j = 0; j < 8; j++) {
            float o = di * a[j] + bgs[j];
            rb[j] = f2bf(o);
            float back = bf2f((unsigned short)rb[j]);
            s += back; ss += back * back;
        }
        uint4 pk;
        pk.x = rb[0] | (rb[1] << 16);
        pk.y = rb[2] | (rb[3] << 16);
        pk.z = rb[4] | (rb[5] << 16);
        pk.w = rb[6] | (rb[7] << 16);
        *(uint4*)(OUT + (size_t)wid * 128 + t * 8) = pk;
        #pragma unroll
        for (int d = 1; d < 16; d <<= 1) { s += __shfl_xor(s, d); ss += __shfl_xor(ss, d); }
        if (t == 0) STout[wid] = make_float2(s, ss);
    }
}

// H stride 64 (cols 47..63 junk, never written out). 8 edges in flight.
__global__ __launch_bounds__(256) void agg47_kernel(
    const ushortT* __restrict__ H, float* __restrict__ OUT,
    const float* __restrict__ bg, const int* __restrict__ rowptr,
    const int* __restrict__ colv, const float* __restrict__ dinv, int n) {
    int wid = (blockIdx.x * 256 + threadIdx.x) >> 6;
    int lane = threadIdx.x & 63;
    if (wid >= n) return;
    int g = lane >> 3, t = lane & 7;
    float di = dinv[wid];
    float a[8] = {0.f, 0.f, 0.f, 0.f, 0.f, 0.f, 0.f, 0.f};
    if (g == 0) unpack_add(*(const uint4*)(H + (size_t)wid * 64 + t * 8), a);  // self
    int e0 = rowptr[wid], e1 = rowptr[wid + 1];
    for (int e = e0 + g; e < e1; e += 8) {
        int s = colv[e];
        unpack_add(*(const uint4*)(H + (size_t)s * 64 + t * 8), a);
    }
    #pragma unroll
    for (int j = 0; j < 8; j++) {
        a[j] += __shfl_xor(a[j], 8);
        a[j] += __shfl_xor(a[j], 16);
        a[j] += __shfl_xor(a[j], 32);
    }
    if (g == 0) {
        #pragma unroll
        for (int j = 0; j < 8; j++) {
            int c = t * 8 + j;
            if (c < 47) OUT[(size_t)wid * 47 + c] = di * a[j] + bg[c];
        }
    }
}

// ---------------- launcher ----------------

extern "C" void kernel_launch(void* const* d_in, const int* in_sizes, int n_in,
                              void* d_out, int out_size, void* d_ws, size_t ws_size,
                              hipStream_t stream) {
    const float* x = (const float*)d_in[0];
    const int* ei = (const int*)d_in[1];
    const float* lng0 = (const float*)d_in[2];
    const float* lnb0 = (const float*)d_in[3];
    const float* Ws0 = (const float*)d_in[4];
    const float* bs0 = (const float*)d_in[5];
    const float* Wb0 = (const float*)d_in[6];
    const float* bb0 = (const float*)d_in[7];
    const float* bg0 = (const float*)d_in[8];
    const float* lng1 = (const float*)d_in[9];
    const float* lnb1 = (const float*)d_in[10];
    const float* Ws1 = (const float*)d_in[11];
    const float* bs1 = (const float*)d_in[12];
    const float* Wb1 = (const float*)d_in[13];
    const float* bb1 = (const float*)d_in[14];
    const float* bg1 = (const float*)d_in[15];
    const float* lng2 = (const float*)d_in[16];
    const float* lnb2 = (const float*)d_in[17];
    const float* Ws2 = (const float*)d_in[18];
    const float* bs2 = (const float*)d_in[19];
    const float* Wb2 = (const float*)d_in[20];
    const float* bb2 = (const float*)d_in[21];
    const float* bg2 = (const float*)d_in[22];

    const int N = in_sizes[0] / 128;
    const int E = in_sizes[1] / 2;

    char* wsp = (char*)d_ws;
    size_t off = 0;
    auto alloc = [&](size_t bytes) {
        off = (off + 255) & ~(size_t)255;
        void* p = wsp + off;
        off += bytes;
        return p;
    };
    int* cur = (int*)alloc((size_t)N * 4);
    int* rowptr = (int*)alloc((size_t)(N + 1) * 4);
    int* bsum = (int*)alloc(1024 * 4);
    int* colv = (int*)alloc((size_t)E * 4);
    float* dinvv = (float*)alloc((size_t)N * 4);
    ushortT* hbuf = (ushortT*)alloc((size_t)N * 128 * 2);
    ushortT* a1 = (ushortT*)alloc((size_t)N * 128 * 2);
    ushortT* a2 = (ushortT*)alloc((size_t)N * 128 * 2);
    float2* stx = (float2*)alloc((size_t)N * 8);
    float2* st1 = (float2*)alloc((size_t)N * 8);
    float2* st2 = (float2*)alloc((size_t)N * 8);
    ushortT* Wc0 = (ushortT*)alloc((size_t)128 * 640 * 2);
    ushortT* Wc1 = (ushortT*)alloc((size_t)128 * 640 * 2);
    ushortT* Wc2 = (ushortT*)alloc((size_t)47 * 1920 * 2);
    size_t off_base = off;
    ushortT* xb = (ushortT*)alloc((size_t)N * 128 * 2);  // bf16 mirror of x
    bool fits = (off <= ws_size);
    if (!fits) off = off_base;
    (void)n_in; (void)out_size;

    const int* srcp = ei;
    const int* dstp = ei + E;

    int gN = (N + 255) / 256;
    int gE = (E + 255) / 256;
    int nb = (N + 1023) / 1024;
    int gF = (N + 127) / 128;
    int gW = (N + 3) / 4;

    build_wc<<<(128 * 640 + 255) / 256, 256, 0, stream>>>(Ws0, Wb0, Wc0, 128, 128);
    build_wc<<<(128 * 640 + 255) / 256, 256, 0, stream>>>(Ws1, Wb1, Wc1, 128, 128);
    build_wc<<<(47 * 1920 + 255) / 256, 256, 0, stream>>>(Ws2, Wb2, Wc2, 47, 384);

    zero_ints<<<gN, 256, 0, stream>>>(cur, N);
    hist_kernel<<<gE, 256, 0, stream>>>(dstp, cur, E, N);
    scanA<<<nb, 256, 0, stream>>>(cur, rowptr, bsum, N);
    scanB<<<1, 64, 0, stream>>>(bsum, nb);
    scanC<<<nb, 256, 0, stream>>>(rowptr, bsum, N, E);
    dinv_cur_kernel<<<gN, 256, 0, stream>>>(rowptr, dinvv, cur, N);
    fill_kernel<<<gE, 256, 0, stream>>>(srcp, dstp, cur, colv, E, N);
    stats_f32<<<gW, 256, 0, stream>>>(x, stx, fits ? xb : nullptr, N);

    // layer 1
    if (fits)
        fkan_kernel<1, 128, 0><<<gF, 256, 0, stream>>>(xb, 128, xb, 128, xb, 128, stx, stx, stx,
                                                       lng0, lnb0, Wc0, bs0, bb0, dinvv, hbuf, 128, N);
    else
        fkan_kernel<1, 128, 1><<<gF, 256, 0, stream>>>(x, 128, x, 128, x, 128, stx, stx, stx,
                                                       lng0, lnb0, Wc0, bs0, bb0, dinvv, hbuf, 128, N);
    agg128_kernel<<<gW, 256, 0, stream>>>(hbuf, a1, bg0, rowptr, colv, dinvv, st1, N);

    // layer 2
    fkan_kernel<1, 128, 0><<<gF, 256, 0, stream>>>(a1, 128, a1, 128, a1, 128, st1, st1, st1,
                                                   lng1, lnb1, Wc1, bs1, bb1, dinvv, hbuf, 128, N);
    agg128_kernel<<<gW, 256, 0, stream>>>(hbuf, a2, bg1, rowptr, colv, dinvv, st2, N);

    // layer 3 (hbuf stride 64)
    if (fits)
        fkan_kernel<3, 47, 0><<<gF, 256, 0, stream>>>(xb, 128, a1, 128, a2, 128, stx, st1, st2,
                                                      lng2, lnb2, Wc2, bs2, bb2, dinvv, hbuf, 64, N);
    else
        fkan_kernel<3, 47, 1><<<gF, 256, 0, stream>>>(x, 128, a1, 128, a2, 128, stx, st1, st2,
                                                      lng2, lnb2, Wc2, bs2, bb2, dinvv, hbuf, 64, N);
    agg47_kernel<<<gW, 256, 0, stream>>>(hbuf, (float*)d_out, bg2, rowptr, colv, dinvv, N);
}